// Round 3
// baseline (735.270 us; speedup 1.0000x reference)
//
#include <hip/hip_runtime.h>
#include <hip/hip_bf16.h>
#include <math.h>

#define B_SZ   16384
#define IN_SZ  512
#define CH_SZ  1024
#define ED_SZ  4096
#define NC_SZ  8
#define NE_SZ  512
#define D_SZ   512

typedef short short8 __attribute__((ext_vector_type(8)));
typedef float f32x4 __attribute__((ext_vector_type(4)));

__device__ __forceinline__ ushort f2bf(float f) {
  union { float f; unsigned u; } v; v.f = f;
  unsigned u = v.u;
  return (ushort)((u + 0x7fffu + ((u >> 16) & 1u)) >> 16);  // RNE
}
__device__ __forceinline__ float bf2f(ushort h) {
  union { unsigned u; float f; } v; v.u = ((unsigned)h) << 16; return v.f;
}

__device__ __forceinline__ void gload_lds16(const void* g, void* l) {
  __builtin_amdgcn_global_load_lds(
      (const __attribute__((address_space(1))) void*)g,
      (__attribute__((address_space(3))) void*)l, 16, 0, 0);
}

// ===================== 256x256 8-phase GEMM core =====================
// 512 threads = 8 waves (2M x 4N distributed halves). BK=64, 2-buffer LDS,
// XOR-swizzled slots (involution pre-applied on global source), counted vmcnt.
// Wave (wm,wn) output: rows hA*128+wm*64+[0,64), cols hB*128+wn*32+[0,32).
// acc[hA][m][hB][n] f32x4.  Issue order per tile: A0,B0,B1,A1.

#define RD_A(P) _Pragma("unroll") for (int m=0;m<4;++m){ int ar=wm*64+m*16+c0; int sw=(ar&7)<<4; \
  _Pragma("unroll") for (int ks=0;ks<2;++ks) af[m][ks]=*(const short8*)((P)+ar*64+((((ks<<6)|gsh)^sw)>>1)); }
#define RD_B(P) _Pragma("unroll") for (int n=0;n<2;++n){ int br=wn*32+n*16+c0; int sw=(br&7)<<4; \
  _Pragma("unroll") for (int ks=0;ks<2;++ks) bfr[n][ks]=*(const short8*)((P)+br*64+((((ks<<6)|gsh)^sw)>>1)); }
#define MM(HA,HB) _Pragma("unroll") for (int m=0;m<4;++m) _Pragma("unroll") for (int n=0;n<2;++n){ \
  acc[HA][m][HB][n]=__builtin_amdgcn_mfma_f32_16x16x32_bf16(af[m][0],bfr[n][0],acc[HA][m][HB][n],0,0,0); \
  acc[HA][m][HB][n]=__builtin_amdgcn_mfma_f32_16x16x32_bf16(af[m][1],bfr[n][1],acc[HA][m][HB][n],0,0,0); }
#define WAITV(N) asm volatile("s_waitcnt vmcnt(" #N ")" ::: "memory")
#define BAR()    asm volatile("s_barrier" ::: "memory")

template<int NT>
__device__ __forceinline__ void gemm256(
    const ushort* __restrict__ A, int lda, int aBase,
    const ushort* __restrict__ Bt, int ldb, int bBase,
    ushort* sA, ushort* sB, f32x4 (&acc)[2][4][2][2])
{
  const int tid = threadIdx.x;
  const int lane = tid & 63;
  const int w = tid >> 6;
  const int wm = w >> 2, wn = w & 3;
  const int g = lane >> 4, c0 = lane & 15;
  const int gsh = g << 4;

  const int f0 = tid, f1 = 512 + tid;
  const int r0 = f0 >> 3, r1 = f1 >> 3;
  const int cs0 = ((f0 & 7) ^ (r0 & 7)) * 8, cs1 = ((f1 & 7) ^ (r1 & 7)) * 8;
  const ushort* aS0 = A + (size_t)(aBase + r0)*lda + cs0;
  const ushort* aS1 = A + (size_t)(aBase + r1)*lda + cs1;
  const ushort* bS0 = Bt + (size_t)(bBase + r0)*ldb + cs0;
  const ushort* bS1 = Bt + (size_t)(bBase + r1)*ldb + cs1;
  const size_t a128 = (size_t)128*lda, b128 = (size_t)128*ldb;

  auto issue = [&](int si) {
    int tt = si >> 2, q = si & 3, kt = tt << 6, buf2 = (tt & 1) * 2;
    if (q == 0)      { ushort* d = sA +  buf2   *8192; gload_lds16(aS0 + kt,        d + f0*8); gload_lds16(aS1 + kt,        d + f1*8); }
    else if (q == 1) { ushort* d = sB +  buf2   *8192; gload_lds16(bS0 + kt,        d + f0*8); gload_lds16(bS1 + kt,        d + f1*8); }
    else if (q == 2) { ushort* d = sB + (buf2+1)*8192; gload_lds16(bS0 + b128 + kt, d + f0*8); gload_lds16(bS1 + b128 + kt, d + f1*8); }
    else             { ushort* d = sA + (buf2+1)*8192; gload_lds16(aS0 + a128 + kt, d + f0*8); gload_lds16(aS1 + a128 + kt, d + f1*8); }
  };

  #pragma unroll
  for (int hA=0;hA<2;++hA)
    #pragma unroll
    for (int m=0;m<4;++m)
      #pragma unroll
      for (int hB=0;hB<2;++hB)
        #pragma unroll
        for (int n=0;n<2;++n) acc[hA][m][hB][n] = (f32x4){0.f,0.f,0.f,0.f};

  issue(0); issue(1); issue(2); issue(3);
  WAITV(4); BAR();

  for (int t = 0; t < NT-1; ++t) {
    const int buf2 = (t & 1) * 2;
    const ushort* pA0 = sA +  buf2   *8192;
    const ushort* pA1 = sA + (buf2+1)*8192;
    const ushort* pB0 = sB +  buf2   *8192;
    const ushort* pB1 = sB + (buf2+1)*8192;
    short8 af[4][2], bfr[2][2];
    RD_A(pA0); RD_B(pB0);
    issue(4*t+4);
    WAITV(4); BAR();
    __builtin_amdgcn_s_setprio(1); MM(0,0); __builtin_amdgcn_s_setprio(0);
    BAR();
    RD_B(pB1);
    issue(4*t+5);
    WAITV(4); BAR();
    __builtin_amdgcn_s_setprio(1); MM(0,1); __builtin_amdgcn_s_setprio(0);
    BAR();
    RD_A(pA1); RD_B(pB0);
    issue(4*t+6);
    WAITV(6); BAR();
    __builtin_amdgcn_s_setprio(1); MM(1,0); __builtin_amdgcn_s_setprio(0);
    BAR();
    RD_B(pB1);
    issue(4*t+7);
    WAITV(4); BAR();
    __builtin_amdgcn_s_setprio(1); MM(1,1); __builtin_amdgcn_s_setprio(0);
    BAR();
  }
  { // peeled last tile (drain)
    const int buf2 = ((NT-1) & 1) * 2;
    const ushort* pA0 = sA +  buf2   *8192;
    const ushort* pA1 = sA + (buf2+1)*8192;
    const ushort* pB0 = sB +  buf2   *8192;
    const ushort* pB1 = sB + (buf2+1)*8192;
    short8 af[4][2], bfr[2][2];
    RD_A(pA0); RD_B(pB0);
    WAITV(2); BAR();
    __builtin_amdgcn_s_setprio(1); MM(0,0); __builtin_amdgcn_s_setprio(0);
    BAR();
    RD_B(pB1);
    WAITV(0); BAR();
    __builtin_amdgcn_s_setprio(1); MM(0,1); __builtin_amdgcn_s_setprio(0);
    RD_A(pA1); RD_B(pB0);
    MM(1,0);
    RD_B(pB1);
    MM(1,1);
  }
}

// ---------- 256^2 kernels (single 128KB smem; epilogue staged in LDS) ------
template<int NT, int NBN>
__global__ __launch_bounds__(512, 2) void k256_bias_relu(
    const ushort* __restrict__ A, int lda,
    const ushort* __restrict__ Bt, int ldb,
    const float* __restrict__ bias, ushort* __restrict__ Cout, int ldc)
{
  __shared__ ushort smem[65536];                  // 128 KiB
  ushort* sA = smem;                              // 64 KiB (2buf x 2half x 128x64)
  ushort* sB = smem + 32768;                      // 64 KiB
  f32x4 acc[2][4][2][2];
  int nwg = gridDim.x, bid = blockIdx.x;
  int swz = (bid & 7)*(nwg >> 3) + (bid >> 3);
  int mBase = (swz / NBN) * 256, nBase = (swz % NBN) * 256;
  gemm256<NT>(A, lda, mBase, Bt, ldb, nBase, sA, sB, acc);
  const int lane = threadIdx.x & 63, w = threadIdx.x >> 6;
  const int wm = w >> 2, wn = w & 3, g = lane >> 4, c0 = lane & 15;
  __syncthreads();                                // all LDS reads done; reuse as C stage
  #pragma unroll
  for (int hA=0;hA<2;++hA)
    #pragma unroll
    for (int m=0;m<4;++m)
      #pragma unroll
      for (int hB=0;hB<2;++hB)
        #pragma unroll
        for (int n=0;n<2;++n) {
          int lcol = hB*128 + wn*32 + n*16 + c0;
          float bb = bias[nBase + lcol];
          #pragma unroll
          for (int r=0;r<4;++r) {
            int lrow = hA*128 + wm*64 + m*16 + g*4 + r;
            smem[lrow*256 + lcol] = f2bf(fmaxf(acc[hA][m][hB][n][r] + bb, 0.f));
          }
        }
  __syncthreads();
  #pragma unroll
  for (int p=0;p<16;++p) {
    int row = p*16 + (threadIdx.x >> 5);
    short8 v = *(const short8*)(smem + row*256 + (threadIdx.x & 31)*8);
    *(short8*)(Cout + (size_t)(mBase + row)*ldc + nBase + (threadIdx.x & 31)*8) = v;
  }
}

__global__ __launch_bounds__(512, 2) void k256_z(
    const ushort* __restrict__ A, const ushort* __restrict__ Bt,
    const float* __restrict__ bq, ushort* __restrict__ Z, float* __restrict__ zz)
{
  __shared__ ushort smem[65536];
  ushort* sA = smem;
  ushort* sB = smem + 32768;
  f32x4 acc[2][4][2][2];
  int nwg = gridDim.x, bid = blockIdx.x;
  int swz = (bid & 7)*(nwg >> 3) + (bid >> 3);
  int mBase = (swz >> 4) * 256, nBase = (swz & 15) * 256;
  gemm256<16>(A, CH_SZ, mBase, Bt, CH_SZ, nBase, sA, sB, acc);
  const int lane = threadIdx.x & 63, w = threadIdx.x >> 6;
  const int wm = w >> 2, wn = w & 3, g = lane >> 4, c0 = lane & 15;
  const int cb = nBase >> 9;
  __syncthreads();
  #pragma unroll
  for (int hA=0;hA<2;++hA)
    #pragma unroll
    for (int m=0;m<4;++m)
      #pragma unroll
      for (int r=0;r<4;++r) {
        int lrow = hA*128 + wm*64 + m*16 + g*4 + r;
        float s = 0.f;
        #pragma unroll
        for (int hB=0;hB<2;++hB)
          #pragma unroll
          for (int n=0;n<2;++n) {
            int lcol = hB*128 + wn*32 + n*16 + c0;
            float v = acc[hA][m][hB][n][r] + bq[nBase + lcol];
            ushort hb = f2bf(v);
            smem[lrow*256 + lcol] = hb;
            float vb = bf2f(hb);
            s += vb*vb;
          }
        s += __shfl_xor(s,1); s += __shfl_xor(s,2);
        s += __shfl_xor(s,4); s += __shfl_xor(s,8);
        if (c0 == 0) atomicAdd(&zz[(mBase + lrow)*NC_SZ + cb], s);
      }
  __syncthreads();
  #pragma unroll
  for (int p=0;p<16;++p) {
    int row = p*16 + (threadIdx.x >> 5);
    short8 v = *(const short8*)(smem + row*256 + (threadIdx.x & 31)*8);
    *(short8*)(Z + (size_t)(mBase + row)*ED_SZ + nBase + (threadIdx.x & 31)*8) = v;
  }
}

__global__ __launch_bounds__(512, 2) void k256_dist(
    const ushort* __restrict__ Zb, const ushort* __restrict__ embT,
    const float* __restrict__ e_sq, float* __restrict__ pval, int* __restrict__ pidx)
{
  __shared__ ushort smem[65536];
  ushort* sA = smem;
  ushort* sB = smem + 32768;
  f32x4 acc[2][4][2][2];
  const int c = blockIdx.z;
  const int mBase = blockIdx.x * 256, nBase = blockIdx.y * 256;
  const ushort* A  = Zb + (size_t)c * D_SZ;            // lda = ED
  const ushort* Bt = embT + (size_t)c * NE_SZ * D_SZ;  // [ne][d]
  gemm256<8>(A, ED_SZ, mBase, Bt, D_SZ, nBase, sA, sB, acc);
  const int lane = threadIdx.x & 63, w = threadIdx.x >> 6;
  const int wm = w >> 2, wn = w & 3, g = lane >> 4, c0 = lane & 15;
  const float* esq = e_sq + c*NE_SZ;
  #pragma unroll
  for (int hA=0;hA<2;++hA)
    #pragma unroll
    for (int m=0;m<4;++m)
      #pragma unroll
      for (int r=0;r<4;++r) {
        float bvv = 3.0e38f; int bii = 0;
        #pragma unroll
        for (int hB=0;hB<2;++hB)
          #pragma unroll
          for (int n=0;n<2;++n) {
            int col = nBase + hB*128 + wn*32 + n*16 + c0;
            float v = esq[col] - 2.0f*acc[hA][m][hB][n][r];
            if (v < bvv) { bvv = v; bii = col; }
          }
        #pragma unroll
        for (int off=1; off<16; off<<=1) {
          float ov = __shfl_xor(bvv, off);
          int   oi = __shfl_xor(bii, off);
          if (ov < bvv || (ov == bvv && oi < bii)) { bvv = ov; bii = oi; }
        }
        if (c0 == 0) {
          int row = mBase + hA*128 + wm*64 + m*16 + g*4 + r;
          int slot = ((row*NC_SZ + c) << 3) + (blockIdx.y*4 + wn);
          pval[slot] = bvv; pidx[slot] = bii;
        }
      }
}

// ===================== small/legacy kernels =====================
template<int BM, int BN>
__device__ __forceinline__ void gemm_core(
    const ushort* __restrict__ A, int lda, int aBase,
    const ushort* __restrict__ Bt, int ldb, int bBase,
    int K,
    ushort (&sA)[BM][64], ushort (&sB)[BN][64],
    f32x4 (&acc)[BM/32][BN/32])
{
  constexpr int MF = BM/32, NF = BN/32;
  const int tid = threadIdx.x;
  const int lane = tid & 63;
  const int w = tid >> 6;
  const int g = lane >> 4, c0 = lane & 15;
  const int wrow = (w >> 1) * (BM/2), wcol = (w & 1) * (BN/2);

  #pragma unroll
  for (int m=0;m<MF;m++)
    #pragma unroll
    for (int n=0;n<NF;n++) acc[m][n] = (f32x4){0.f,0.f,0.f,0.f};

  for (int kt = 0; kt < K; kt += 64) {
    #pragma unroll
    for (int i = 0; i < BM/32; ++i) {
      int f = i*256 + tid;
      int r = f >> 3, cc = f & 7;
      gload_lds16(A + (size_t)(aBase + r)*lda + (kt + cc*8), &sA[r][cc*8]);
    }
    #pragma unroll
    for (int i = 0; i < BN/32; ++i) {
      int f = i*256 + tid;
      int r = f >> 3, cc = f & 7;
      gload_lds16(Bt + (size_t)(bBase + r)*ldb + (kt + cc*8), &sB[r][cc*8]);
    }
    __syncthreads();
    #pragma unroll
    for (int ks = 0; ks < 64; ks += 32) {
      short8 av[MF], bv2[NF];
      #pragma unroll
      for (int m=0;m<MF;m++)
        av[m] = *(const short8*)(&sA[wrow + m*16 + c0][ks + g*8]);
      #pragma unroll
      for (int n=0;n<NF;n++)
        bv2[n] = *(const short8*)(&sB[wcol + n*16 + c0][ks + g*8]);
      #pragma unroll
      for (int m=0;m<MF;m++)
        #pragma unroll
        for (int n=0;n<NF;n++)
          acc[m][n] = __builtin_amdgcn_mfma_f32_16x16x32_bf16(av[m], bv2[n], acc[m][n], 0, 0, 0);
    }
    __syncthreads();
  }
}

__global__ __launch_bounds__(256) void k_cvt(const float* __restrict__ s,
                                             ushort* __restrict__ d, int n) {
  int i = (blockIdx.x*256 + threadIdx.x)*4;
  if (i + 3 < n) {
    float4 v = *(const float4*)(s + i);
    ushort4 o;
    o.x = f2bf(v.x); o.y = f2bf(v.y); o.z = f2bf(v.z); o.w = f2bf(v.w);
    *(ushort4*)(d + i) = o;
  }
}

__global__ __launch_bounds__(256) void k_pad_wx2(const float* __restrict__ s,
                                                 ushort* __restrict__ d) {
  int i = blockIdx.x*256 + threadIdx.x;
  int row = i >> 10, col = i & 1023;
  d[i] = (row < 63) ? f2bf(s[row*1024 + col]) : (ushort)0;
}

__global__ void k_embT(const float* __restrict__ embed,
                       ushort* __restrict__ embT, float* __restrict__ e_sq) {
  __shared__ float t[32][33];
  int c = blockIdx.x, d0 = blockIdx.y*32, n0 = blockIdx.z*32;
  const float* src = embed + ((size_t)c*D_SZ + d0)*NE_SZ + n0;
  for (int dy = threadIdx.y; dy < 32; dy += 8)
    t[dy][threadIdx.x] = src[(size_t)dy*NE_SZ + threadIdx.x];
  __syncthreads();
  ushort* dst = embT + ((size_t)c*NE_SZ + n0)*D_SZ + d0;
  for (int ny = threadIdx.y; ny < 32; ny += 8)
    dst[(size_t)ny*D_SZ + threadIdx.x] = f2bf(t[threadIdx.x][ny]);
  if (threadIdx.y == 0) {
    float s = 0.f;
    #pragma unroll
    for (int dd = 0; dd < 32; ++dd) { float v = t[dd][threadIdx.x]; s += v*v; }
    atomicAdd(&e_sq[c*NE_SZ + n0 + threadIdx.x], s);
  }
}

__global__ __launch_bounds__(256) void k_gemm_dec(
    const ushort* __restrict__ H1, const ushort* __restrict__ Wx2b,
    const float* __restrict__ b_x2, const float* __restrict__ Wd1,
    const float* __restrict__ bd1, const float* __restrict__ Wd2,
    const float* __restrict__ bd2, float* __restrict__ dec)
{
  __shared__ ushort sA[64][64], sB[64][64];
  __shared__ float semb[64][65];
  f32x4 acc[2][2];
  int mBase = blockIdx.x*64;
  gemm_core<64,64>(H1, CH_SZ, mBase, Wx2b, CH_SZ, 0, CH_SZ, sA, sB, acc);
  int lane = threadIdx.x&63, w = threadIdx.x>>6;
  int g = lane>>4, c0 = lane&15, wrow = (w>>1)*32, wcol = (w&1)*32;
  #pragma unroll
  for (int m=0;m<2;m++)
    #pragma unroll
    for (int n=0;n<2;n++) {
      int col = wcol + n*16 + c0;
      float bb = (col < 63) ? b_x2[col] : 0.f;
      #pragma unroll
      for (int r=0;r<4;r++)
        semb[wrow + m*16 + g*4 + r][col] = acc[m][n][r] + bb;
    }
  __syncthreads();
  if (threadIdx.x < 64) {
    int lrow = threadIdx.x;
    float o = bd2[0];
    for (int j=0;j<63;++j) {
      float s = bd1[j];
      #pragma unroll 7
      for (int i=0;i<63;++i) s += semb[lrow][i]*Wd1[j*63+i];
      o += fmaxf(s, 0.f)*Wd2[j];
    }
    dec[mBase + lrow] = o;
  }
}

__global__ __launch_bounds__(256) void k_argmin_reduce(
    const float* __restrict__ pval, const int* __restrict__ pidx,
    const float* __restrict__ zz, int* __restrict__ counts,
    float* __restrict__ dacc)
{
  int t = blockIdx.x*256 + threadIdx.x;
  float bvv = 3.0e38f; int bii = 0;
  #pragma unroll
  for (int nb=0; nb<8; ++nb) {
    float v = pval[(t<<3)+nb];
    if (v < bvv) { bvv = v; bii = pidx[(t<<3)+nb]; }
  }
  int c = t & 7;
  atomicAdd(&counts[c*NE_SZ + bii], 1);
  float dm = bvv + zz[t];
  #pragma unroll
  for (int off=1; off<64; off<<=1) dm += __shfl_xor(dm, off);
  if ((threadIdx.x&63) == 0) atomicAdd(dacc, dm);
}

__global__ __launch_bounds__(256) void k_final(const int* __restrict__ counts,
                                               const float* __restrict__ dacc,
                                               float* __restrict__ out) {
  double s = 0.0;
  for (int i = threadIdx.x; i < NC_SZ*NE_SZ; i += 256) {
    double p = (double)counts[i] / (double)B_SZ;
    s -= p * log(p + 1e-10);
  }
  #pragma unroll
  for (int off=1; off<64; off<<=1) s += __shfl_xor(s, off);
  __shared__ double wsum[4];
  if ((threadIdx.x&63) == 0) wsum[threadIdx.x>>6] = s;
  __syncthreads();
  if (threadIdx.x == 0) {
    double e = wsum[0]+wsum[1]+wsum[2]+wsum[3];
    out[B_SZ]   = (float)((double)dacc[0] / ((double)B_SZ * (double)D_SZ));
    out[B_SZ+1] = (float)exp(e);
  }
}

extern "C" void kernel_launch(void* const* d_in, const int* in_sizes, int n_in,
                              void* d_out, int out_size, void* d_ws, size_t ws_size,
                              hipStream_t stream) {
  (void)in_sizes; (void)n_in; (void)out_size; (void)ws_size;
  const float* x    = (const float*)d_in[0];
  const float* W_f  = (const float*)d_in[1];
  const float* b_f  = (const float*)d_in[2];
  const float* W_x1 = (const float*)d_in[3];
  const float* b_x1 = (const float*)d_in[4];
  const float* W_x2 = (const float*)d_in[5];
  const float* b_x2 = (const float*)d_in[6];
  const float* Wq   = (const float*)d_in[7];
  const float* bq   = (const float*)d_in[8];
  const float* Wd1  = (const float*)d_in[9];
  const float* bd1  = (const float*)d_in[10];
  const float* Wd2  = (const float*)d_in[11];
  const float* bd2  = (const float*)d_in[12];
  const float* embed= (const float*)d_in[13];
  float* out = (float*)d_out;

  char* ws = (char*)d_ws;
  size_t off = 0;
  auto alloc = [&](size_t bytes) {
    void* p = ws + off; off = (off + bytes + 255) & ~(size_t)255; return p;
  };
  ushort* xb    = (ushort*)alloc((size_t)B_SZ*IN_SZ*2);
  ushort* preb  = (ushort*)alloc((size_t)B_SZ*CH_SZ*2);
  ushort* h1b   = (ushort*)alloc((size_t)B_SZ*CH_SZ*2);
  ushort* zb    = (ushort*)alloc((size_t)B_SZ*ED_SZ*2);
  ushort* wfb   = (ushort*)alloc((size_t)CH_SZ*IN_SZ*2);
  ushort* wx1b  = (ushort*)alloc((size_t)CH_SZ*IN_SZ*2);
  ushort* wqb   = (ushort*)alloc((size_t)ED_SZ*CH_SZ*2);
  ushort* wx2b  = (ushort*)alloc((size_t)64*CH_SZ*2);
  ushort* embTb = (ushort*)alloc((size_t)NC_SZ*NE_SZ*D_SZ*2);
  float*  esq   = (float*)alloc((size_t)NC_SZ*NE_SZ*4);
  float*  zz    = (float*)alloc((size_t)B_SZ*NC_SZ*4);
  float*  pval  = (float*)alloc((size_t)B_SZ*NC_SZ*8*4);
  int*    pidx  = (int*)alloc((size_t)B_SZ*NC_SZ*8*4);
  int*    counts= (int*)alloc(4096*4);
  float*  dacc  = (float*)alloc(256);

  hipMemsetAsync(esq, 0, (size_t)NC_SZ*NE_SZ*4, stream);
  hipMemsetAsync(zz, 0, (size_t)B_SZ*NC_SZ*4, stream);
  hipMemsetAsync(counts, 0, 4096*4, stream);
  hipMemsetAsync(dacc, 0, 4, stream);

  k_cvt<<<(B_SZ*IN_SZ/4+255)/256, 256, 0, stream>>>(x, xb, B_SZ*IN_SZ);
  k_cvt<<<(CH_SZ*IN_SZ/4+255)/256, 256, 0, stream>>>(W_f, wfb, CH_SZ*IN_SZ);
  k_cvt<<<(CH_SZ*IN_SZ/4+255)/256, 256, 0, stream>>>(W_x1, wx1b, CH_SZ*IN_SZ);
  k_cvt<<<(ED_SZ*CH_SZ/4+255)/256, 256, 0, stream>>>(Wq, wqb, ED_SZ*CH_SZ);
  k_pad_wx2<<<(64*CH_SZ)/256, 256, 0, stream>>>(W_x2, wx2b);
  k_embT<<<dim3(NC_SZ, D_SZ/32, NE_SZ/32), dim3(32,8), 0, stream>>>(embed, embTb, esq);

  // pre = relu(x @ W_f^T + b_f)   [16384 x 1024, K=512]
  k256_bias_relu<8,4><<<(B_SZ/256)*(CH_SZ/256), 512, 0, stream>>>(
      xb, IN_SZ, wfb, IN_SZ, b_f, preb, CH_SZ);
  // h1 = relu(x @ W_x1^T + b_x1)
  k256_bias_relu<8,4><<<(B_SZ/256)*(CH_SZ/256), 512, 0, stream>>>(
      xb, IN_SZ, wx1b, IN_SZ, b_x1, h1b, CH_SZ);
  // z = pre @ Wq^T + bq  (+ per-codebook ||z||^2)
  k256_z<<<(B_SZ/256)*(ED_SZ/256), 512, 0, stream>>>(preb, wqb, bq, zb, zz);
  // emb = h1 @ W_x2^T + b_x2 ; dec = decoder(emb)
  k_gemm_dec<<<dim3(B_SZ/64), 256, 0, stream>>>(h1b, wx2b, b_x2, Wd1, bd1, Wd2, bd2, out);
  // dist partial argmin per codebook
  k256_dist<<<dim3(B_SZ/256, NE_SZ/256, NC_SZ), 512, 0, stream>>>(
      zb, embTb, esq, pval, pidx);
  k_argmin_reduce<<<(B_SZ*NC_SZ)/256, 256, 0, stream>>>(pval, pidx, zz, counts, dacc);
  k_final<<<1, 256, 0, stream>>>(counts, dacc, out);
}

// Round 4
// 715.607 us; speedup vs baseline: 1.0275x; 1.0275x over previous
//
#include <hip/hip_runtime.h>
#include <hip/hip_bf16.h>
#include <math.h>

#define B_SZ   16384
#define IN_SZ  512
#define CH_SZ  1024
#define ED_SZ  4096
#define NC_SZ  8
#define NE_SZ  512
#define D_SZ   512

typedef short short8 __attribute__((ext_vector_type(8)));
typedef float f32x4 __attribute__((ext_vector_type(4)));

__device__ __forceinline__ ushort f2bf(float f) {
  union { float f; unsigned u; } v; v.f = f;
  unsigned u = v.u;
  return (ushort)((u + 0x7fffu + ((u >> 16) & 1u)) >> 16);  // RNE
}
__device__ __forceinline__ float bf2f(ushort h) {
  union { unsigned u; float f; } v; v.u = ((unsigned)h) << 16; return v.f;
}

__device__ __forceinline__ void gload_lds16(const void* g, void* l) {
  __builtin_amdgcn_global_load_lds(
      (const __attribute__((address_space(1))) void*)g,
      (__attribute__((address_space(3))) void*)l, 16, 0, 0);
}

// ===================== 256x256 GEMM core, v2 schedule =====================
// 8 waves (2M x 4N). BK=64, 2-buffer LDS, XOR-swizzled slots (involution
// pre-applied on global source). v2: B-frags for BOTH halves hoisted in ph0
// (24 ds_read_b128/wave/K-tile instead of 32), 2 barriers per K-tile, vmcnt
// ledger: issue A0@ph0, B0+B1@ph1, A1@ph3; force A1(t) @ph1 WAITV(6),
// force A0/B0/B1(t+1) @ph3 WAITV(2). Every arrival: WAITV then BAR before RD.

#define RD_A(P) _Pragma("unroll") for (int m=0;m<4;++m){ int ar=wm*64+m*16+c0; int sw=(ar&7)<<4; \
  _Pragma("unroll") for (int ks=0;ks<2;++ks) af[m][ks]=*(const short8*)((P)+ar*64+((((ks<<6)|gsh)^sw)>>1)); }
#define RD_B_H(H,P) _Pragma("unroll") for (int n=0;n<2;++n){ int br=wn*32+n*16+c0; int sw=(br&7)<<4; \
  _Pragma("unroll") for (int ks=0;ks<2;++ks) bfr[H][n][ks]=*(const short8*)((P)+br*64+((((ks<<6)|gsh)^sw)>>1)); }
#define MM(HA,HB) _Pragma("unroll") for (int m=0;m<4;++m) _Pragma("unroll") for (int n=0;n<2;++n){ \
  acc[HA][m][HB][n]=__builtin_amdgcn_mfma_f32_16x16x32_bf16(af[m][0],bfr[HB][n][0],acc[HA][m][HB][n],0,0,0); \
  acc[HA][m][HB][n]=__builtin_amdgcn_mfma_f32_16x16x32_bf16(af[m][1],bfr[HB][n][1],acc[HA][m][HB][n],0,0,0); }
#define WAITV(N) asm volatile("s_waitcnt vmcnt(" #N ")" ::: "memory")
#define BAR()    asm volatile("s_barrier" ::: "memory")
#define SP1()    __builtin_amdgcn_s_setprio(1)
#define SP0()    __builtin_amdgcn_s_setprio(0)

template<int NT>
__device__ __forceinline__ void gemm256(
    const ushort* __restrict__ A, int lda, int aBase,
    const ushort* __restrict__ Bt, int ldb, int bBase,
    ushort* sA, ushort* sB, f32x4 (&acc)[2][4][2][2])
{
  const int tid = threadIdx.x;
  const int lane = tid & 63;
  const int w = tid >> 6;
  const int wm = w >> 2, wn = w & 3;
  const int g = lane >> 4, c0 = lane & 15;
  const int gsh = g << 4;

  const int f0 = tid, f1 = 512 + tid;
  const int r0 = f0 >> 3, r1 = f1 >> 3;
  const int cs0 = ((f0 & 7) ^ (r0 & 7)) * 8, cs1 = ((f1 & 7) ^ (r1 & 7)) * 8;
  const ushort* aS0 = A + (size_t)(aBase + r0)*lda + cs0;
  const ushort* aS1 = A + (size_t)(aBase + r1)*lda + cs1;
  const ushort* bS0 = Bt + (size_t)(bBase + r0)*ldb + cs0;
  const ushort* bS1 = Bt + (size_t)(bBase + r1)*ldb + cs1;
  const size_t a128 = (size_t)128*lda, b128 = (size_t)128*ldb;

  auto issue = [&](int si) {
    int tt = si >> 2, q = si & 3, kt = tt << 6, buf2 = (tt & 1) * 2;
    if (q == 0)      { ushort* d = sA +  buf2   *8192; gload_lds16(aS0 + kt,        d + f0*8); gload_lds16(aS1 + kt,        d + f1*8); }
    else if (q == 1) { ushort* d = sB +  buf2   *8192; gload_lds16(bS0 + kt,        d + f0*8); gload_lds16(bS1 + kt,        d + f1*8); }
    else if (q == 2) { ushort* d = sB + (buf2+1)*8192; gload_lds16(bS0 + b128 + kt, d + f0*8); gload_lds16(bS1 + b128 + kt, d + f1*8); }
    else             { ushort* d = sA + (buf2+1)*8192; gload_lds16(aS0 + a128 + kt, d + f0*8); gload_lds16(aS1 + a128 + kt, d + f1*8); }
  };

  #pragma unroll
  for (int hA=0;hA<2;++hA)
    #pragma unroll
    for (int m=0;m<4;++m)
      #pragma unroll
      for (int hB=0;hB<2;++hB)
        #pragma unroll
        for (int n=0;n<2;++n) acc[hA][m][hB][n] = (f32x4){0.f,0.f,0.f,0.f};

  issue(0); issue(1); issue(2); issue(3);   // tile 0: A0,B0,B1,A1
  WAITV(2); BAR();                          // force A0,B0,B1(0); A1(0) in flight

  for (int t = 0; t < NT-1; ++t) {
    const int buf2 = (t & 1) * 2;
    const ushort* pA0 = sA +  buf2   *8192;
    const ushort* pA1 = sA + (buf2+1)*8192;
    const ushort* pB0 = sB +  buf2   *8192;
    const ushort* pB1 = sB + (buf2+1)*8192;
    short8 af[4][2], bfr[2][2][2];
    // ph0: read A0 + both B halves; issue A0(t+1)
    RD_A(pA0); RD_B_H(0,pB0); RD_B_H(1,pB1);
    issue(4*t+4);
    SP1(); MM(0,0); SP0();
    // ph1: issue B0,B1(t+1); force A1(t); publish before ph2's RD_A1
    issue(4*t+5); issue(4*t+6);
    WAITV(6);
    SP1(); MM(0,1); SP0();
    BAR();
    // ph2: read A1 (no issue, no wait)
    RD_A(pA1);
    SP1(); MM(1,0); SP0();
    // ph3: issue A1(t+1); force A0,B0,B1(t+1); publish for next ph0
    issue(4*t+7);
    WAITV(2);
    SP1(); MM(1,1); SP0();
    BAR();
  }
  { // peeled last tile: in-flight = A1(last)
    const int buf2 = ((NT-1) & 1) * 2;
    const ushort* pA0 = sA +  buf2   *8192;
    const ushort* pA1 = sA + (buf2+1)*8192;
    const ushort* pB0 = sB +  buf2   *8192;
    const ushort* pB1 = sB + (buf2+1)*8192;
    short8 af[4][2], bfr[2][2][2];
    RD_A(pA0); RD_B_H(0,pB0); RD_B_H(1,pB1);
    SP1(); MM(0,0); SP0();
    WAITV(0);                               // force A1(last)
    SP1(); MM(0,1); SP0();
    BAR();                                  // publish A1 before RD
    RD_A(pA1);
    SP1(); MM(1,0); MM(1,1); SP0();
  }
}

// ---------- 256^2 kernels (single 128KB smem; epilogue staged in LDS) ------
template<int NT, int NBN>
__global__ __launch_bounds__(512, 2) void k256_bias_relu(
    const ushort* __restrict__ A, int lda,
    const ushort* __restrict__ Bt, int ldb,
    const float* __restrict__ bias, ushort* __restrict__ Cout, int ldc)
{
  __shared__ ushort smem[65536];                  // 128 KiB
  ushort* sA = smem;
  ushort* sB = smem + 32768;
  f32x4 acc[2][4][2][2];
  int nwg = gridDim.x, bid = blockIdx.x;
  int swz = (bid & 7)*(nwg >> 3) + (bid >> 3);
  int mBase = (swz / NBN) * 256, nBase = (swz % NBN) * 256;
  gemm256<NT>(A, lda, mBase, Bt, ldb, nBase, sA, sB, acc);
  const int lane = threadIdx.x & 63, w = threadIdx.x >> 6;
  const int wm = w >> 2, wn = w & 3, g = lane >> 4, c0 = lane & 15;
  __syncthreads();                                // all LDS reads done; reuse as C stage
  #pragma unroll
  for (int hA=0;hA<2;++hA)
    #pragma unroll
    for (int m=0;m<4;++m)
      #pragma unroll
      for (int hB=0;hB<2;++hB)
        #pragma unroll
        for (int n=0;n<2;++n) {
          int lcol = hB*128 + wn*32 + n*16 + c0;
          float bb = bias[nBase + lcol];
          #pragma unroll
          for (int r=0;r<4;++r) {
            int lrow = hA*128 + wm*64 + m*16 + g*4 + r;
            smem[lrow*256 + lcol] = f2bf(fmaxf(acc[hA][m][hB][n][r] + bb, 0.f));
          }
        }
  __syncthreads();
  #pragma unroll
  for (int p=0;p<16;++p) {
    int row = p*16 + (threadIdx.x >> 5);
    short8 v = *(const short8*)(smem + row*256 + (threadIdx.x & 31)*8);
    *(short8*)(Cout + (size_t)(mBase + row)*ldc + nBase + (threadIdx.x & 31)*8) = v;
  }
}

__global__ __launch_bounds__(512, 2) void k256_z(
    const ushort* __restrict__ A, const ushort* __restrict__ Bt,
    const float* __restrict__ bq, ushort* __restrict__ Z, float* __restrict__ zz)
{
  __shared__ ushort smem[65536];
  ushort* sA = smem;
  ushort* sB = smem + 32768;
  f32x4 acc[2][4][2][2];
  int nwg = gridDim.x, bid = blockIdx.x;
  int swz = (bid & 7)*(nwg >> 3) + (bid >> 3);
  int mBase = (swz >> 4) * 256, nBase = (swz & 15) * 256;
  gemm256<16>(A, CH_SZ, mBase, Bt, CH_SZ, nBase, sA, sB, acc);
  const int lane = threadIdx.x & 63, w = threadIdx.x >> 6;
  const int wm = w >> 2, wn = w & 3, g = lane >> 4, c0 = lane & 15;
  const int cb = nBase >> 9;
  __syncthreads();
  #pragma unroll
  for (int hA=0;hA<2;++hA)
    #pragma unroll
    for (int m=0;m<4;++m)
      #pragma unroll
      for (int r=0;r<4;++r) {
        int lrow = hA*128 + wm*64 + m*16 + g*4 + r;
        float s = 0.f;
        #pragma unroll
        for (int hB=0;hB<2;++hB)
          #pragma unroll
          for (int n=0;n<2;++n) {
            int lcol = hB*128 + wn*32 + n*16 + c0;
            float v = acc[hA][m][hB][n][r] + bq[nBase + lcol];
            ushort hb = f2bf(v);
            smem[lrow*256 + lcol] = hb;
            float vb = bf2f(hb);
            s += vb*vb;
          }
        s += __shfl_xor(s,1); s += __shfl_xor(s,2);
        s += __shfl_xor(s,4); s += __shfl_xor(s,8);
        if (c0 == 0) atomicAdd(&zz[(mBase + lrow)*NC_SZ + cb], s);
      }
  __syncthreads();
  #pragma unroll
  for (int p=0;p<16;++p) {
    int row = p*16 + (threadIdx.x >> 5);
    short8 v = *(const short8*)(smem + row*256 + (threadIdx.x & 31)*8);
    *(short8*)(Z + (size_t)(mBase + row)*ED_SZ + nBase + (threadIdx.x & 31)*8) = v;
  }
}

__global__ __launch_bounds__(512, 2) void k256_dist(
    const ushort* __restrict__ Zb, const ushort* __restrict__ embT,
    const float* __restrict__ e_sq, float* __restrict__ pval, int* __restrict__ pidx)
{
  __shared__ ushort smem[65536];
  ushort* sA = smem;
  ushort* sB = smem + 32768;
  f32x4 acc[2][4][2][2];
  const int c = blockIdx.z;
  const int mBase = blockIdx.x * 256, nBase = blockIdx.y * 256;
  const ushort* A  = Zb + (size_t)c * D_SZ;            // lda = ED
  const ushort* Bt = embT + (size_t)c * NE_SZ * D_SZ;  // [ne][d]
  gemm256<8>(A, ED_SZ, mBase, Bt, D_SZ, nBase, sA, sB, acc);
  const int lane = threadIdx.x & 63, w = threadIdx.x >> 6;
  const int wm = w >> 2, wn = w & 3, g = lane >> 4, c0 = lane & 15;
  const float* esq = e_sq + c*NE_SZ;
  #pragma unroll
  for (int hA=0;hA<2;++hA)
    #pragma unroll
    for (int m=0;m<4;++m)
      #pragma unroll
      for (int r=0;r<4;++r) {
        float bvv = 3.0e38f; int bii = 0;
        #pragma unroll
        for (int hB=0;hB<2;++hB)
          #pragma unroll
          for (int n=0;n<2;++n) {
            int col = nBase + hB*128 + wn*32 + n*16 + c0;
            float v = esq[col] - 2.0f*acc[hA][m][hB][n][r];
            if (v < bvv) { bvv = v; bii = col; }
          }
        #pragma unroll
        for (int off=1; off<16; off<<=1) {
          float ov = __shfl_xor(bvv, off);
          int   oi = __shfl_xor(bii, off);
          if (ov < bvv || (ov == bvv && oi < bii)) { bvv = ov; bii = oi; }
        }
        if (c0 == 0) {
          int row = mBase + hA*128 + wm*64 + m*16 + g*4 + r;
          int slot = ((row*NC_SZ + c) << 3) + (blockIdx.y*4 + wn);
          pval[slot] = bvv; pidx[slot] = bii;
        }
      }
}

// ===================== small/legacy kernels =====================
template<int BM, int BN>
__device__ __forceinline__ void gemm_core(
    const ushort* __restrict__ A, int lda, int aBase,
    const ushort* __restrict__ Bt, int ldb, int bBase,
    int K,
    ushort (&sA)[BM][64], ushort (&sB)[BN][64],
    f32x4 (&acc)[BM/32][BN/32])
{
  constexpr int MF = BM/32, NF = BN/32;
  const int tid = threadIdx.x;
  const int lane = tid & 63;
  const int w = tid >> 6;
  const int g = lane >> 4, c0 = lane & 15;
  const int wrow = (w >> 1) * (BM/2), wcol = (w & 1) * (BN/2);

  #pragma unroll
  for (int m=0;m<MF;m++)
    #pragma unroll
    for (int n=0;n<NF;n++) acc[m][n] = (f32x4){0.f,0.f,0.f,0.f};

  for (int kt = 0; kt < K; kt += 64) {
    #pragma unroll
    for (int i = 0; i < BM/32; ++i) {
      int f = i*256 + tid;
      int r = f >> 3, cc = f & 7;
      gload_lds16(A + (size_t)(aBase + r)*lda + (kt + cc*8), &sA[r][cc*8]);
    }
    #pragma unroll
    for (int i = 0; i < BN/32; ++i) {
      int f = i*256 + tid;
      int r = f >> 3, cc = f & 7;
      gload_lds16(Bt + (size_t)(bBase + r)*ldb + (kt + cc*8), &sB[r][cc*8]);
    }
    __syncthreads();
    #pragma unroll
    for (int ks = 0; ks < 64; ks += 32) {
      short8 av[MF], bv2[NF];
      #pragma unroll
      for (int m=0;m<MF;m++)
        av[m] = *(const short8*)(&sA[wrow + m*16 + c0][ks + g*8]);
      #pragma unroll
      for (int n=0;n<NF;n++)
        bv2[n] = *(const short8*)(&sB[wcol + n*16 + c0][ks + g*8]);
      #pragma unroll
      for (int m=0;m<MF;m++)
        #pragma unroll
        for (int n=0;n<NF;n++)
          acc[m][n] = __builtin_amdgcn_mfma_f32_16x16x32_bf16(av[m], bv2[n], acc[m][n], 0, 0, 0);
    }
    __syncthreads();
  }
}

__global__ __launch_bounds__(256) void k_cvt(const float* __restrict__ s,
                                             ushort* __restrict__ d, int n) {
  int i = (blockIdx.x*256 + threadIdx.x)*4;
  if (i + 3 < n) {
    float4 v = *(const float4*)(s + i);
    ushort4 o;
    o.x = f2bf(v.x); o.y = f2bf(v.y); o.z = f2bf(v.z); o.w = f2bf(v.w);
    *(ushort4*)(d + i) = o;
  }
}

__global__ __launch_bounds__(256) void k_pad_wx2(const float* __restrict__ s,
                                                 ushort* __restrict__ d) {
  int i = blockIdx.x*256 + threadIdx.x;
  int row = i >> 10, col = i & 1023;
  d[i] = (row < 63) ? f2bf(s[row*1024 + col]) : (ushort)0;
}

__global__ void k_embT(const float* __restrict__ embed,
                       ushort* __restrict__ embT, float* __restrict__ e_sq) {
  __shared__ float t[32][33];
  int c = blockIdx.x, d0 = blockIdx.y*32, n0 = blockIdx.z*32;
  const float* src = embed + ((size_t)c*D_SZ + d0)*NE_SZ + n0;
  for (int dy = threadIdx.y; dy < 32; dy += 8)
    t[dy][threadIdx.x] = src[(size_t)dy*NE_SZ + threadIdx.x];
  __syncthreads();
  ushort* dst = embT + ((size_t)c*NE_SZ + n0)*D_SZ + d0;
  for (int ny = threadIdx.y; ny < 32; ny += 8)
    dst[(size_t)ny*D_SZ + threadIdx.x] = f2bf(t[threadIdx.x][ny]);
  if (threadIdx.y == 0) {
    float s = 0.f;
    #pragma unroll
    for (int dd = 0; dd < 32; ++dd) { float v = t[dd][threadIdx.x]; s += v*v; }
    atomicAdd(&e_sq[c*NE_SZ + n0 + threadIdx.x], s);
  }
}

__global__ __launch_bounds__(256) void k_gemm_dec(
    const ushort* __restrict__ H1, const ushort* __restrict__ Wx2b,
    const float* __restrict__ b_x2, const float* __restrict__ Wd1,
    const float* __restrict__ bd1, const float* __restrict__ Wd2,
    const float* __restrict__ bd2, float* __restrict__ dec)
{
  __shared__ ushort sA[64][64], sB[64][64];
  __shared__ float semb[64][65];
  f32x4 acc[2][2];
  int mBase = blockIdx.x*64;
  gemm_core<64,64>(H1, CH_SZ, mBase, Wx2b, CH_SZ, 0, CH_SZ, sA, sB, acc);
  int lane = threadIdx.x&63, w = threadIdx.x>>6;
  int g = lane>>4, c0 = lane&15, wrow = (w>>1)*32, wcol = (w&1)*32;
  #pragma unroll
  for (int m=0;m<2;m++)
    #pragma unroll
    for (int n=0;n<2;n++) {
      int col = wcol + n*16 + c0;
      float bb = (col < 63) ? b_x2[col] : 0.f;
      #pragma unroll
      for (int r=0;r<4;r++)
        semb[wrow + m*16 + g*4 + r][col] = acc[m][n][r] + bb;
    }
  __syncthreads();
  if (threadIdx.x < 64) {
    int lrow = threadIdx.x;
    float o = bd2[0];
    for (int j=0;j<63;++j) {
      float s = bd1[j];
      #pragma unroll 7
      for (int i=0;i<63;++i) s += semb[lrow][i]*Wd1[j*63+i];
      o += fmaxf(s, 0.f)*Wd2[j];
    }
    dec[mBase + lrow] = o;
  }
}

__global__ __launch_bounds__(256) void k_argmin_reduce(
    const float* __restrict__ pval, const int* __restrict__ pidx,
    const float* __restrict__ zz, int* __restrict__ counts,
    float* __restrict__ dacc)
{
  int t = blockIdx.x*256 + threadIdx.x;
  float bvv = 3.0e38f; int bii = 0;
  #pragma unroll
  for (int nb=0; nb<8; ++nb) {
    float v = pval[(t<<3)+nb];
    if (v < bvv) { bvv = v; bii = pidx[(t<<3)+nb]; }
  }
  int c = t & 7;
  atomicAdd(&counts[c*NE_SZ + bii], 1);
  float dm = bvv + zz[t];
  #pragma unroll
  for (int off=1; off<64; off<<=1) dm += __shfl_xor(dm, off);
  if ((threadIdx.x&63) == 0) atomicAdd(dacc, dm);
}

__global__ __launch_bounds__(256) void k_final(const int* __restrict__ counts,
                                               const float* __restrict__ dacc,
                                               float* __restrict__ out) {
  double s = 0.0;
  for (int i = threadIdx.x; i < NC_SZ*NE_SZ; i += 256) {
    double p = (double)counts[i] / (double)B_SZ;
    s -= p * log(p + 1e-10);
  }
  #pragma unroll
  for (int off=1; off<64; off<<=1) s += __shfl_xor(s, off);
  __shared__ double wsum[4];
  if ((threadIdx.x&63) == 0) wsum[threadIdx.x>>6] = s;
  __syncthreads();
  if (threadIdx.x == 0) {
    double e = wsum[0]+wsum[1]+wsum[2]+wsum[3];
    out[B_SZ]   = (float)((double)dacc[0] / ((double)B_SZ * (double)D_SZ));
    out[B_SZ+1] = (float)exp(e);
  }
}

extern "C" void kernel_launch(void* const* d_in, const int* in_sizes, int n_in,
                              void* d_out, int out_size, void* d_ws, size_t ws_size,
                              hipStream_t stream) {
  (void)in_sizes; (void)n_in; (void)out_size; (void)ws_size;
  const float* x    = (const float*)d_in[0];
  const float* W_f  = (const float*)d_in[1];
  const float* b_f  = (const float*)d_in[2];
  const float* W_x1 = (const float*)d_in[3];
  const float* b_x1 = (const float*)d_in[4];
  const float* W_x2 = (const float*)d_in[5];
  const float* b_x2 = (const float*)d_in[6];
  const float* Wq   = (const float*)d_in[7];
  const float* bq   = (const float*)d_in[8];
  const float* Wd1  = (const float*)d_in[9];
  const float* bd1  = (const float*)d_in[10];
  const float* Wd2  = (const float*)d_in[11];
  const float* bd2  = (const float*)d_in[12];
  const float* embed= (const float*)d_in[13];
  float* out = (float*)d_out;

  char* ws = (char*)d_ws;
  size_t off = 0;
  auto alloc = [&](size_t bytes) {
    void* p = ws + off; off = (off + bytes + 255) & ~(size_t)255; return p;
  };
  ushort* xb    = (ushort*)alloc((size_t)B_SZ*IN_SZ*2);
  ushort* preb  = (ushort*)alloc((size_t)B_SZ*CH_SZ*2);
  ushort* h1b   = (ushort*)alloc((size_t)B_SZ*CH_SZ*2);
  ushort* zb    = (ushort*)alloc((size_t)B_SZ*ED_SZ*2);
  ushort* wfb   = (ushort*)alloc((size_t)CH_SZ*IN_SZ*2);
  ushort* wx1b  = (ushort*)alloc((size_t)CH_SZ*IN_SZ*2);
  ushort* wqb   = (ushort*)alloc((size_t)ED_SZ*CH_SZ*2);
  ushort* wx2b  = (ushort*)alloc((size_t)64*CH_SZ*2);
  ushort* embTb = (ushort*)alloc((size_t)NC_SZ*NE_SZ*D_SZ*2);
  float*  esq   = (float*)alloc((size_t)NC_SZ*NE_SZ*4);
  float*  zz    = (float*)alloc((size_t)B_SZ*NC_SZ*4);
  float*  pval  = (float*)alloc((size_t)B_SZ*NC_SZ*8*4);
  int*    pidx  = (int*)alloc((size_t)B_SZ*NC_SZ*8*4);
  int*    counts= (int*)alloc(4096*4);
  float*  dacc  = (float*)alloc(256);

  hipMemsetAsync(esq, 0, (size_t)NC_SZ*NE_SZ*4, stream);
  hipMemsetAsync(zz, 0, (size_t)B_SZ*NC_SZ*4, stream);
  hipMemsetAsync(counts, 0, 4096*4, stream);
  hipMemsetAsync(dacc, 0, 4, stream);

  k_cvt<<<(B_SZ*IN_SZ/4+255)/256, 256, 0, stream>>>(x, xb, B_SZ*IN_SZ);
  k_cvt<<<(CH_SZ*IN_SZ/4+255)/256, 256, 0, stream>>>(W_f, wfb, CH_SZ*IN_SZ);
  k_cvt<<<(CH_SZ*IN_SZ/4+255)/256, 256, 0, stream>>>(W_x1, wx1b, CH_SZ*IN_SZ);
  k_cvt<<<(ED_SZ*CH_SZ/4+255)/256, 256, 0, stream>>>(Wq, wqb, ED_SZ*CH_SZ);
  k_pad_wx2<<<(64*CH_SZ)/256, 256, 0, stream>>>(W_x2, wx2b);
  k_embT<<<dim3(NC_SZ, D_SZ/32, NE_SZ/32), dim3(32,8), 0, stream>>>(embed, embTb, esq);

  // pre = relu(x @ W_f^T + b_f)   [16384 x 1024, K=512]
  k256_bias_relu<8,4><<<(B_SZ/256)*(CH_SZ/256), 512, 0, stream>>>(
      xb, IN_SZ, wfb, IN_SZ, b_f, preb, CH_SZ);
  // h1 = relu(x @ W_x1^T + b_x1)
  k256_bias_relu<8,4><<<(B_SZ/256)*(CH_SZ/256), 512, 0, stream>>>(
      xb, IN_SZ, wx1b, IN_SZ, b_x1, h1b, CH_SZ);
  // z = pre @ Wq^T + bq  (+ per-codebook ||z||^2)
  k256_z<<<(B_SZ/256)*(ED_SZ/256), 512, 0, stream>>>(preb, wqb, bq, zb, zz);
  // emb = h1 @ W_x2^T + b_x2 ; dec = decoder(emb)
  k_gemm_dec<<<dim3(B_SZ/64), 256, 0, stream>>>(h1b, wx2b, b_x2, Wd1, bd1, Wd2, bd2, out);
  // dist partial argmin per codebook
  k256_dist<<<dim3(B_SZ/256, NE_SZ/256, NC_SZ), 512, 0, stream>>>(
      zb, embTb, esq, pval, pidx);
  k_argmin_reduce<<<(B_SZ*NC_SZ)/256, 256, 0, stream>>>(pval, pidx, zz, counts, dacc);
  k_final<<<1, 256, 0, stream>>>(counts, dacc, out);
}

// Round 5
// 635.078 us; speedup vs baseline: 1.1578x; 1.1268x over previous
//
#include <hip/hip_runtime.h>
#include <hip/hip_bf16.h>
#include <math.h>

#define B_SZ   16384
#define IN_SZ  512
#define CH_SZ  1024
#define ED_SZ  4096
#define NC_SZ  8
#define NE_SZ  512
#define D_SZ   512

typedef short short8 __attribute__((ext_vector_type(8)));
typedef float f32x4 __attribute__((ext_vector_type(4)));

__device__ __forceinline__ ushort f2bf(float f) {
  union { float f; unsigned u; } v; v.f = f;
  unsigned u = v.u;
  return (ushort)((u + 0x7fffu + ((u >> 16) & 1u)) >> 16);  // RNE
}
__device__ __forceinline__ float bf2f(ushort h) {
  union { unsigned u; float f; } v; v.u = ((unsigned)h) << 16; return v.f;
}

__device__ __forceinline__ void gload_lds16(const void* g, void* l) {
  __builtin_amdgcn_global_load_lds(
      (const __attribute__((address_space(1))) void*)g,
      (__attribute__((address_space(3))) void*)l, 16, 0, 0);
}

#define WAITV(N) asm volatile("s_waitcnt vmcnt(" #N ")" ::: "memory")
#define BAR()    asm volatile("s_barrier" ::: "memory")

// ===================== fused z + dist + argmin kernel =====================
// grid: 1024 blocks = (B/128 rows) x (NC codebooks); c = bid&7 (XCD-aligned).
// phase 1: z[128][512] = pre[mBase..][1024] @ Wq[c*512..][1024]^T + bq,
//          K=1024, BK=32, 3-buffer staging (A 8KB + B 32KB per tile).
// phase 2: convert acc -> bf16 Z in LDS (XOR-swizzled), accumulate zz/row.
// phase 3: dist vs embT[c] (512ne x 512d) staged in 8KB (64ne x 64d) tiles,
//          3-buffer; fold per-row (min,argmin); emit counts + dacc.
__global__ __launch_bounds__(512, 2) void k_zdist(
    const ushort* __restrict__ preB, const ushort* __restrict__ WqB,
    const float* __restrict__ bq, const ushort* __restrict__ embT,
    const float* __restrict__ esq, int* __restrict__ counts,
    float* __restrict__ dacc)
{
  __shared__ ushort smem[80128];                 // 160256 B
  const int tid = threadIdx.x;
  const int lane = tid & 63;
  const int w = tid >> 6;
  const int wm = w >> 2, wn = w & 3;             // 2M x 4N waves
  const int g = lane >> 4, c0 = lane & 15;
  const int bid = blockIdx.x;
  const int c = bid & 7;
  const int mBase = (bid >> 3) * 128;

  // ---------------- phase 1: z-GEMM ----------------
  // staging ptrs (source column pre-swizzled; LDS dest linear)
  const int arow = tid >> 2, aslot = tid & 3;
  const ushort* aSrc = preB + (size_t)(mBase + arow)*CH_SZ + ((aslot ^ (arow & 3))*8);
  const ushort* bSrc0; const ushort* bSrc1; const ushort* bSrc2; const ushort* bSrc3;
  {
    int f0 = tid, f1 = 512+tid, f2 = 1024+tid, f3 = 1536+tid;
    bSrc0 = WqB + (size_t)(c*512 + (f0>>2))*CH_SZ + (((f0&3) ^ ((f0>>2)&3))*8);
    bSrc1 = WqB + (size_t)(c*512 + (f1>>2))*CH_SZ + (((f1&3) ^ ((f1>>2)&3))*8);
    bSrc2 = WqB + (size_t)(c*512 + (f2>>2))*CH_SZ + (((f2&3) ^ ((f2>>2)&3))*8);
    bSrc3 = WqB + (size_t)(c*512 + (f3>>2))*CH_SZ + (((f3&3) ^ ((f3>>2)&3))*8);
  }
  auto issue_z = [&](int t) {
    int buf = t % 3, kt = t * 32;
    gload_lds16(aSrc + kt, smem + buf*4096 + tid*8);
    ushort* db = smem + 12288 + buf*16384;
    gload_lds16(bSrc0 + kt, db + tid*8);
    gload_lds16(bSrc1 + kt, db + (512+tid)*8);
    gload_lds16(bSrc2 + kt, db + (1024+tid)*8);
    gload_lds16(bSrc3 + kt, db + (1536+tid)*8);
  };

  f32x4 acc[4][8];
  #pragma unroll
  for (int m=0;m<4;++m)
    #pragma unroll
    for (int n=0;n<8;++n) acc[m][n] = (f32x4){0.f,0.f,0.f,0.f};

  issue_z(0); issue_z(1);
  WAITV(5); BAR();

  for (int t = 0; t < 32; ++t) {
    const int buf = t % 3;
    const ushort* pA = smem + buf*4096;
    const ushort* pB = smem + 12288 + buf*16384;
    short8 af[4];
    #pragma unroll
    for (int m=0;m<4;++m) {
      int ar = wm*64 + m*16 + c0;
      af[m] = *(const short8*)(pA + ar*32 + ((((g<<4) ^ ((ar&3)<<4)))>>1));
    }
    if (t+2 < 32) issue_z(t+2);
    #pragma unroll
    for (int nh=0;nh<2;++nh) {
      short8 bf[4];
      #pragma unroll
      for (int n=0;n<4;++n) {
        int br = wn*128 + nh*64 + n*16 + c0;
        bf[n] = *(const short8*)(pB + br*32 + ((((g<<4) ^ ((br&3)<<4)))>>1));
      }
      __builtin_amdgcn_s_setprio(1);
      #pragma unroll
      for (int m=0;m<4;++m)
        #pragma unroll
        for (int n=0;n<4;++n)
          acc[m][nh*4+n] = __builtin_amdgcn_mfma_f32_16x16x32_bf16(af[m], bf[n], acc[m][nh*4+n], 0, 0, 0);
      __builtin_amdgcn_s_setprio(0);
    }
    if (t+2 < 32) { WAITV(5); } else { WAITV(0); }
    BAR();
  }

  // ---------------- phase 2: acc -> Z_lds (bf16, swizzled) + zz ----------
  float* zzl = (float*)(smem + 77824);           // 128 floats
  if (tid < 128) zzl[tid] = 0.f;
  BAR();
  #pragma unroll
  for (int m=0;m<4;++m) {
    float sq[4] = {0.f,0.f,0.f,0.f};
    #pragma unroll
    for (int n=0;n<8;++n) {
      int lcol = wn*128 + n*16 + c0;
      float bb = bq[c*512 + lcol];
      #pragma unroll
      for (int r=0;r<4;++r) {
        int row = wm*64 + m*16 + g*4 + r;
        float v = acc[m][n][r] + bb;
        ushort hb = f2bf(v);
        int byte = row*1024 + ((lcol*2) ^ ((row&7)<<4));
        smem[byte>>1] = hb;
        float vb = bf2f(hb);
        sq[r] += vb*vb;
      }
    }
    #pragma unroll
    for (int r=0;r<4;++r) {
      float s = sq[r];
      s += __shfl_xor(s,1); s += __shfl_xor(s,2);
      s += __shfl_xor(s,4); s += __shfl_xor(s,8);
      if (c0 == 0) atomicAdd(&zzl[wm*64 + m*16 + g*4 + r], s);
    }
  }

  // ---------------- phase 3: dist + argmin ----------------
  const int erow = tid >> 3, eslot = tid & 7;
  auto issue_emb = [&](int s) {
    int net = s >> 3, ks = s & 7, buf = s % 3;
    const ushort* src = embT + ((size_t)(c*512 + net*64 + erow))*512
                        + ks*64 + ((eslot ^ (erow&7))*8);
    gload_lds16(src, smem + 65536 + buf*4096 + tid*8);
  };
  issue_emb(0); issue_emb(1);
  BAR();                                          // conversion published

  float rv[4][4]; int ri[4][4];
  #pragma unroll
  for (int m=0;m<4;++m)
    #pragma unroll
    for (int r=0;r<4;++r) { rv[m][r] = 3.0e38f; ri[m][r] = 0; }

  f32x4 acc2[4];
  for (int s = 0; s < 64; ++s) {
    const int net = s >> 3, ks = s & 7, buf = s % 3;
    if (s < 63) { WAITV(1); } else { WAITV(0); }
    BAR();
    const ushort* pE = smem + 65536 + buf*4096;
    short8 afd[4][2], bfd[2];
    #pragma unroll
    for (int kk=0;kk<2;++kk) {
      int br = wn*16 + c0;
      bfd[kk] = *(const short8*)(pE + ((br*128 + ((kk*64 + (g<<4)) ^ ((br&7)<<4)))>>1));
      #pragma unroll
      for (int m=0;m<4;++m) {
        int ar = wm*64 + m*16 + c0;
        afd[m][kk] = *(const short8*)(smem + ((ar*1024 + ((ks*128 + kk*64 + (g<<4)) ^ ((ar&7)<<4)))>>1));
      }
    }
    if (s+2 < 64) issue_emb(s+2);
    if (ks == 0) {
      #pragma unroll
      for (int m=0;m<4;++m) acc2[m] = (f32x4){0.f,0.f,0.f,0.f};
    }
    __builtin_amdgcn_s_setprio(1);
    #pragma unroll
    for (int m=0;m<4;++m) {
      acc2[m] = __builtin_amdgcn_mfma_f32_16x16x32_bf16(afd[m][0], bfd[0], acc2[m], 0, 0, 0);
      acc2[m] = __builtin_amdgcn_mfma_f32_16x16x32_bf16(afd[m][1], bfd[1], acc2[m], 0, 0, 0);
    }
    __builtin_amdgcn_s_setprio(0);
    if (ks == 7) {
      float ev = esq[c*512 + net*64 + wn*16 + c0];
      int idx = net*64 + wn*16 + c0;
      #pragma unroll
      for (int m=0;m<4;++m)
        #pragma unroll
        for (int r=0;r<4;++r) {
          float v = ev - 2.0f*acc2[m][r];
          if (v < rv[m][r]) { rv[m][r] = v; ri[m][r] = idx; }
        }
    }
  }

  // cross-lane (c0) fold, then publish per-wave per-row results
  float* pvl = (float*)(smem + 78080);           // [128][4]
  int*   pil = (int*)(smem + 79104);             // [128][4]
  #pragma unroll
  for (int m=0;m<4;++m)
    #pragma unroll
    for (int r=0;r<4;++r) {
      float bv = rv[m][r]; int bi = ri[m][r];
      #pragma unroll
      for (int off=1; off<16; off<<=1) {
        float ov = __shfl_xor(bv, off);
        int   oi = __shfl_xor(bi, off);
        if (ov < bv || (ov == bv && oi < bi)) { bv = ov; bi = oi; }
      }
      if (c0 == 0) {
        int row = wm*64 + m*16 + g*4 + r;
        pvl[row*4 + wn] = bv; pil[row*4 + wn] = bi;
      }
    }
  BAR();

  float dm = 0.f;
  if (tid < 128) {
    int row = tid;
    float bv = pvl[row*4]; int bi = pil[row*4];
    #pragma unroll
    for (int q=1;q<4;++q) {
      float ov = pvl[row*4+q]; int oi = pil[row*4+q];
      if (ov < bv || (ov == bv && oi < bi)) { bv = ov; bi = oi; }
    }
    atomicAdd(&counts[c*NE_SZ + bi], 1);
    dm = bv + zzl[row];
  }
  #pragma unroll
  for (int off=1; off<64; off<<=1) dm += __shfl_xor(dm, off);
  if (lane == 0) atomicAdd(dacc, dm);
}

// ===================== 256x256 GEMM core (bias_relu) =====================
#define RD_A(P) _Pragma("unroll") for (int m=0;m<4;++m){ int ar=wm*64+m*16+c0; int sw=(ar&7)<<4; \
  _Pragma("unroll") for (int ks=0;ks<2;++ks) af[m][ks]=*(const short8*)((P)+ar*64+((((ks<<6)|gsh)^sw)>>1)); }
#define RD_B_H(H,P) _Pragma("unroll") for (int n=0;n<2;++n){ int br=wn*32+n*16+c0; int sw=(br&7)<<4; \
  _Pragma("unroll") for (int ks=0;ks<2;++ks) bfr[H][n][ks]=*(const short8*)((P)+br*64+((((ks<<6)|gsh)^sw)>>1)); }
#define MM(HA,HB) _Pragma("unroll") for (int m=0;m<4;++m) _Pragma("unroll") for (int n=0;n<2;++n){ \
  acc[HA][m][HB][n]=__builtin_amdgcn_mfma_f32_16x16x32_bf16(af[m][0],bfr[HB][n][0],acc[HA][m][HB][n],0,0,0); \
  acc[HA][m][HB][n]=__builtin_amdgcn_mfma_f32_16x16x32_bf16(af[m][1],bfr[HB][n][1],acc[HA][m][HB][n],0,0,0); }

template<int NT>
__device__ __forceinline__ void gemm256(
    const ushort* __restrict__ A, int lda, int aBase,
    const ushort* __restrict__ Bt, int ldb, int bBase,
    ushort* sA, ushort* sB, f32x4 (&acc)[2][4][2][2])
{
  const int tid = threadIdx.x;
  const int lane = tid & 63;
  const int w = tid >> 6;
  const int wm = w >> 2, wn = w & 3;
  const int g = lane >> 4, c0 = lane & 15;
  const int gsh = g << 4;

  const int f0 = tid, f1 = 512 + tid;
  const int r0 = f0 >> 3, r1 = f1 >> 3;
  const int cs0 = ((f0 & 7) ^ (r0 & 7)) * 8, cs1 = ((f1 & 7) ^ (r1 & 7)) * 8;
  const ushort* aS0 = A + (size_t)(aBase + r0)*lda + cs0;
  const ushort* aS1 = A + (size_t)(aBase + r1)*lda + cs1;
  const ushort* bS0 = Bt + (size_t)(bBase + r0)*ldb + cs0;
  const ushort* bS1 = Bt + (size_t)(bBase + r1)*ldb + cs1;
  const size_t a128 = (size_t)128*lda, b128 = (size_t)128*ldb;

  auto issue = [&](int si) {
    int tt = si >> 2, q = si & 3, kt = tt << 6, buf2 = (tt & 1) * 2;
    if (q == 0)      { ushort* d = sA +  buf2   *8192; gload_lds16(aS0 + kt,        d + f0*8); gload_lds16(aS1 + kt,        d + f1*8); }
    else if (q == 1) { ushort* d = sB +  buf2   *8192; gload_lds16(bS0 + kt,        d + f0*8); gload_lds16(bS1 + kt,        d + f1*8); }
    else if (q == 2) { ushort* d = sB + (buf2+1)*8192; gload_lds16(bS0 + b128 + kt, d + f0*8); gload_lds16(bS1 + b128 + kt, d + f1*8); }
    else             { ushort* d = sA + (buf2+1)*8192; gload_lds16(aS0 + a128 + kt, d + f0*8); gload_lds16(aS1 + a128 + kt, d + f1*8); }
  };

  #pragma unroll
  for (int hA=0;hA<2;++hA)
    #pragma unroll
    for (int m=0;m<4;++m)
      #pragma unroll
      for (int hB=0;hB<2;++hB)
        #pragma unroll
        for (int n=0;n<2;++n) acc[hA][m][hB][n] = (f32x4){0.f,0.f,0.f,0.f};

  issue(0); issue(1); issue(2); issue(3);
  WAITV(2); BAR();

  for (int t = 0; t < NT-1; ++t) {
    const int buf2 = (t & 1) * 2;
    const ushort* pA0 = sA +  buf2   *8192;
    const ushort* pA1 = sA + (buf2+1)*8192;
    const ushort* pB0 = sB +  buf2   *8192;
    const ushort* pB1 = sB + (buf2+1)*8192;
    short8 af[4][2], bfr[2][2][2];
    RD_A(pA0); RD_B_H(0,pB0); RD_B_H(1,pB1);
    issue(4*t+4);
    __builtin_amdgcn_s_setprio(1); MM(0,0); __builtin_amdgcn_s_setprio(0);
    issue(4*t+5); issue(4*t+6);
    WAITV(6);
    __builtin_amdgcn_s_setprio(1); MM(0,1); __builtin_amdgcn_s_setprio(0);
    BAR();
    RD_A(pA1);
    __builtin_amdgcn_s_setprio(1); MM(1,0); __builtin_amdgcn_s_setprio(0);
    issue(4*t+7);
    WAITV(2);
    __builtin_amdgcn_s_setprio(1); MM(1,1); __builtin_amdgcn_s_setprio(0);
    BAR();
  }
  {
    const int buf2 = ((NT-1) & 1) * 2;
    const ushort* pA0 = sA +  buf2   *8192;
    const ushort* pA1 = sA + (buf2+1)*8192;
    const ushort* pB0 = sB +  buf2   *8192;
    const ushort* pB1 = sB + (buf2+1)*8192;
    short8 af[4][2], bfr[2][2][2];
    RD_A(pA0); RD_B_H(0,pB0); RD_B_H(1,pB1);
    __builtin_amdgcn_s_setprio(1); MM(0,0); __builtin_amdgcn_s_setprio(0);
    WAITV(0);
    __builtin_amdgcn_s_setprio(1); MM(0,1); __builtin_amdgcn_s_setprio(0);
    BAR();
    RD_A(pA1);
    __builtin_amdgcn_s_setprio(1); MM(1,0); MM(1,1); __builtin_amdgcn_s_setprio(0);
  }
}

template<int NT, int NBN>
__global__ __launch_bounds__(512, 2) void k256_bias_relu(
    const ushort* __restrict__ A, int lda,
    const ushort* __restrict__ Bt, int ldb,
    const float* __restrict__ bias, ushort* __restrict__ Cout, int ldc)
{
  __shared__ ushort smem[65536];
  ushort* sA = smem;
  ushort* sB = smem + 32768;
  f32x4 acc[2][4][2][2];
  int nwg = gridDim.x, bid = blockIdx.x;
  int swz = (bid & 7)*(nwg >> 3) + (bid >> 3);
  int mBase = (swz / NBN) * 256, nBase = (swz % NBN) * 256;
  gemm256<NT>(A, lda, mBase, Bt, ldb, nBase, sA, sB, acc);
  const int lane = threadIdx.x & 63, w = threadIdx.x >> 6;
  const int wm = w >> 2, wn = w & 3, g = lane >> 4, c0 = lane & 15;
  __syncthreads();
  #pragma unroll
  for (int hA=0;hA<2;++hA)
    #pragma unroll
    for (int m=0;m<4;++m)
      #pragma unroll
      for (int hB=0;hB<2;++hB)
        #pragma unroll
        for (int n=0;n<2;++n) {
          int lcol = hB*128 + wn*32 + n*16 + c0;
          float bb = bias[nBase + lcol];
          #pragma unroll
          for (int r=0;r<4;++r) {
            int lrow = hA*128 + wm*64 + m*16 + g*4 + r;
            smem[lrow*256 + lcol] = f2bf(fmaxf(acc[hA][m][hB][n][r] + bb, 0.f));
          }
        }
  __syncthreads();
  #pragma unroll
  for (int p=0;p<16;++p) {
    int row = p*16 + (threadIdx.x >> 5);
    short8 v = *(const short8*)(smem + row*256 + (threadIdx.x & 31)*8);
    *(short8*)(Cout + (size_t)(mBase + row)*ldc + nBase + (threadIdx.x & 31)*8) = v;
  }
}

// ===================== small kernels =====================
template<int BM, int BN>
__device__ __forceinline__ void gemm_core(
    const ushort* __restrict__ A, int lda, int aBase,
    const ushort* __restrict__ Bt, int ldb, int bBase,
    int K,
    ushort (&sA)[BM][64], ushort (&sB)[BN][64],
    f32x4 (&acc)[BM/32][BN/32])
{
  constexpr int MF = BM/32, NF = BN/32;
  const int tid = threadIdx.x;
  const int lane = tid & 63;
  const int w = tid >> 6;
  const int g = lane >> 4, c0 = lane & 15;
  const int wrow = (w >> 1) * (BM/2), wcol = (w & 1) * (BN/2);

  #pragma unroll
  for (int m=0;m<MF;m++)
    #pragma unroll
    for (int n=0;n<NF;n++) acc[m][n] = (f32x4){0.f,0.f,0.f,0.f};

  for (int kt = 0; kt < K; kt += 64) {
    #pragma unroll
    for (int i = 0; i < BM/32; ++i) {
      int f = i*256 + tid;
      int r = f >> 3, cc = f & 7;
      gload_lds16(A + (size_t)(aBase + r)*lda + (kt + cc*8), &sA[r][cc*8]);
    }
    #pragma unroll
    for (int i = 0; i < BN/32; ++i) {
      int f = i*256 + tid;
      int r = f >> 3, cc = f & 7;
      gload_lds16(Bt + (size_t)(bBase + r)*ldb + (kt + cc*8), &sB[r][cc*8]);
    }
    __syncthreads();
    #pragma unroll
    for (int ks = 0; ks < 64; ks += 32) {
      short8 av[MF], bv2[NF];
      #pragma unroll
      for (int m=0;m<MF;m++)
        av[m] = *(const short8*)(&sA[wrow + m*16 + c0][ks + g*8]);
      #pragma unroll
      for (int n=0;n<NF;n++)
        bv2[n] = *(const short8*)(&sB[wcol + n*16 + c0][ks + g*8]);
      #pragma unroll
      for (int m=0;m<MF;m++)
        #pragma unroll
        for (int n=0;n<NF;n++)
          acc[m][n] = __builtin_amdgcn_mfma_f32_16x16x32_bf16(av[m], bv2[n], acc[m][n], 0, 0, 0);
    }
    __syncthreads();
  }
}

__global__ __launch_bounds__(256) void k_cvt(const float* __restrict__ s,
                                             ushort* __restrict__ d, int n) {
  int i = (blockIdx.x*256 + threadIdx.x)*4;
  if (i + 3 < n) {
    float4 v = *(const float4*)(s + i);
    ushort4 o;
    o.x = f2bf(v.x); o.y = f2bf(v.y); o.z = f2bf(v.z); o.w = f2bf(v.w);
    *(ushort4*)(d + i) = o;
  }
}

__global__ __launch_bounds__(256) void k_pad_wx2(const float* __restrict__ s,
                                                 ushort* __restrict__ d) {
  int i = blockIdx.x*256 + threadIdx.x;
  int row = i >> 10, col = i & 1023;
  d[i] = (row < 63) ? f2bf(s[row*1024 + col]) : (ushort)0;
}

__global__ void k_embT(const float* __restrict__ embed,
                       ushort* __restrict__ embT, float* __restrict__ e_sq) {
  __shared__ float t[32][33];
  int c = blockIdx.x, d0 = blockIdx.y*32, n0 = blockIdx.z*32;
  const float* src = embed + ((size_t)c*D_SZ + d0)*NE_SZ + n0;
  for (int dy = threadIdx.y; dy < 32; dy += 8)
    t[dy][threadIdx.x] = src[(size_t)dy*NE_SZ + threadIdx.x];
  __syncthreads();
  ushort* dst = embT + ((size_t)c*NE_SZ + n0)*D_SZ + d0;
  for (int ny = threadIdx.y; ny < 32; ny += 8)
    dst[(size_t)ny*D_SZ + threadIdx.x] = f2bf(t[threadIdx.x][ny]);
  if (threadIdx.y == 0) {
    float s = 0.f;
    #pragma unroll
    for (int dd = 0; dd < 32; ++dd) { float v = t[dd][threadIdx.x]; s += v*v; }
    atomicAdd(&e_sq[c*NE_SZ + n0 + threadIdx.x], s);
  }
}

__global__ __launch_bounds__(256) void k_gemm_dec(
    const ushort* __restrict__ H1, const ushort* __restrict__ Wx2b,
    const float* __restrict__ b_x2, const float* __restrict__ Wd1,
    const float* __restrict__ bd1, const float* __restrict__ Wd2,
    const float* __restrict__ bd2, float* __restrict__ dec)
{
  __shared__ ushort sA[64][64], sB[64][64];
  __shared__ float semb[64][65];
  f32x4 acc[2][2];
  int mBase = blockIdx.x*64;
  gemm_core<64,64>(H1, CH_SZ, mBase, Wx2b, CH_SZ, 0, CH_SZ, sA, sB, acc);
  int lane = threadIdx.x&63, w = threadIdx.x>>6;
  int g = lane>>4, c0 = lane&15, wrow = (w>>1)*32, wcol = (w&1)*32;
  #pragma unroll
  for (int m=0;m<2;m++)
    #pragma unroll
    for (int n=0;n<2;n++) {
      int col = wcol + n*16 + c0;
      float bb = (col < 63) ? b_x2[col] : 0.f;
      #pragma unroll
      for (int r=0;r<4;r++)
        semb[wrow + m*16 + g*4 + r][col] = acc[m][n][r] + bb;
    }
  __syncthreads();
  if (threadIdx.x < 64) {
    int lrow = threadIdx.x;
    float o = bd2[0];
    for (int j=0;j<63;++j) {
      float s = bd1[j];
      #pragma unroll 7
      for (int i=0;i<63;++i) s += semb[lrow][i]*Wd1[j*63+i];
      o += fmaxf(s, 0.f)*Wd2[j];
    }
    dec[mBase + lrow] = o;
  }
}

__global__ __launch_bounds__(256) void k_final(const int* __restrict__ counts,
                                               const float* __restrict__ dacc,
                                               float* __restrict__ out) {
  double s = 0.0;
  for (int i = threadIdx.x; i < NC_SZ*NE_SZ; i += 256) {
    double p = (double)counts[i] / (double)B_SZ;
    s -= p * log(p + 1e-10);
  }
  #pragma unroll
  for (int off=1; off<64; off<<=1) s += __shfl_xor(s, off);
  __shared__ double wsum[4];
  if ((threadIdx.x&63) == 0) wsum[threadIdx.x>>6] = s;
  __syncthreads();
  if (threadIdx.x == 0) {
    double e = wsum[0]+wsum[1]+wsum[2]+wsum[3];
    out[B_SZ]   = (float)((double)dacc[0] / ((double)B_SZ * (double)D_SZ));
    out[B_SZ+1] = (float)exp(e);
  }
}

extern "C" void kernel_launch(void* const* d_in, const int* in_sizes, int n_in,
                              void* d_out, int out_size, void* d_ws, size_t ws_size,
                              hipStream_t stream) {
  (void)in_sizes; (void)n_in; (void)out_size; (void)ws_size;
  const float* x    = (const float*)d_in[0];
  const float* W_f  = (const float*)d_in[1];
  const float* b_f  = (const float*)d_in[2];
  const float* W_x1 = (const float*)d_in[3];
  const float* b_x1 = (const float*)d_in[4];
  const float* W_x2 = (const float*)d_in[5];
  const float* b_x2 = (const float*)d_in[6];
  const float* Wq   = (const float*)d_in[7];
  const float* bq   = (const float*)d_in[8];
  const float* Wd1  = (const float*)d_in[9];
  const float* bd1  = (const float*)d_in[10];
  const float* Wd2  = (const float*)d_in[11];
  const float* bd2  = (const float*)d_in[12];
  const float* embed= (const float*)d_in[13];
  float* out = (float*)d_out;

  char* ws = (char*)d_ws;
  size_t off = 0;
  auto alloc = [&](size_t bytes) {
    void* p = ws + off; off = (off + bytes + 255) & ~(size_t)255; return p;
  };
  ushort* xb    = (ushort*)alloc((size_t)B_SZ*IN_SZ*2);
  ushort* preb  = (ushort*)alloc((size_t)B_SZ*CH_SZ*2);
  ushort* h1b   = (ushort*)alloc((size_t)B_SZ*CH_SZ*2);
  ushort* wfb   = (ushort*)alloc((size_t)CH_SZ*IN_SZ*2);
  ushort* wx1b  = (ushort*)alloc((size_t)CH_SZ*IN_SZ*2);
  ushort* wqb   = (ushort*)alloc((size_t)ED_SZ*CH_SZ*2);
  ushort* wx2b  = (ushort*)alloc((size_t)64*CH_SZ*2);
  ushort* embTb = (ushort*)alloc((size_t)NC_SZ*NE_SZ*D_SZ*2);
  float*  esq   = (float*)alloc((size_t)NC_SZ*NE_SZ*4);
  int*    counts= (int*)alloc(4096*4);
  float*  dacc  = (float*)alloc(256);

  hipMemsetAsync(esq, 0, (size_t)NC_SZ*NE_SZ*4, stream);
  hipMemsetAsync(counts, 0, 4096*4, stream);
  hipMemsetAsync(dacc, 0, 4, stream);

  k_cvt<<<(B_SZ*IN_SZ/4+255)/256, 256, 0, stream>>>(x, xb, B_SZ*IN_SZ);
  k_cvt<<<(CH_SZ*IN_SZ/4+255)/256, 256, 0, stream>>>(W_f, wfb, CH_SZ*IN_SZ);
  k_cvt<<<(CH_SZ*IN_SZ/4+255)/256, 256, 0, stream>>>(W_x1, wx1b, CH_SZ*IN_SZ);
  k_cvt<<<(ED_SZ*CH_SZ/4+255)/256, 256, 0, stream>>>(Wq, wqb, ED_SZ*CH_SZ);
  k_pad_wx2<<<(64*CH_SZ)/256, 256, 0, stream>>>(W_x2, wx2b);
  k_embT<<<dim3(NC_SZ, D_SZ/32, NE_SZ/32), dim3(32,8), 0, stream>>>(embed, embTb, esq);

  // pre = relu(x @ W_f^T + b_f)   [16384 x 1024, K=512]
  k256_bias_relu<8,4><<<(B_SZ/256)*(CH_SZ/256), 512, 0, stream>>>(
      xb, IN_SZ, wfb, IN_SZ, b_f, preb, CH_SZ);
  // h1 = relu(x @ W_x1^T + b_x1)
  k256_bias_relu<8,4><<<(B_SZ/256)*(CH_SZ/256), 512, 0, stream>>>(
      xb, IN_SZ, wx1b, IN_SZ, b_x1, h1b, CH_SZ);
  // fused z-GEMM + dist + argmin (per 128-row x codebook block)
  k_zdist<<<(B_SZ/128)*NC_SZ, 512, 0, stream>>>(preb, wqb, bq, embTb, esq, counts, dacc);
  // emb = h1 @ W_x2^T + b_x2 ; dec = decoder(emb)
  k_gemm_dec<<<dim3(B_SZ/64), 256, 0, stream>>>(h1b, wx2b, b_x2, Wd1, bd1, Wd2, bd2, out);
  k_final<<<1, 256, 0, stream>>>(counts, dacc, out);
}